// Round 14
// baseline (1060.032 us; speedup 1.0000x reference)
//
#include <hip/hip_runtime.h>
#include <hip/hip_bf16.h>

typedef unsigned short ushort_t;
using short8 = __attribute__((ext_vector_type(8))) short;
using f32x4  = __attribute__((ext_vector_type(4))) float;

#define DEVI __device__ __forceinline__

DEVI ushort_t f2bf(float f) {
    union { float f; unsigned u; } c; c.f = f;
    unsigned u = c.u;
    return (ushort_t)((u + 0x7FFF + ((u >> 16) & 1)) >> 16);
}

DEVI f32x4 mfma16(short8 a, short8 b, f32x4 c) {
    return __builtin_amdgcn_mfma_f32_16x16x32_bf16(a, b, c, 0, 0, 0);
}

DEVI void gld16(const void* g, void* l) {
    __builtin_amdgcn_global_load_lds(
        (const __attribute__((address_space(1))) unsigned int*)g,
        (__attribute__((address_space(3))) unsigned int*)l, 16, 0, 0);
}

// ---------------- constants ----------------
#define Bsz 16
#define Ntok 1024
#define Cdim 1152
#define Hn 16
#define Dh 72
#define Dp 96
#define INNER 4608
#define Mrows (Bsz * Ntok)   // 16384

// workspace offsets (bytes)
#define OFF_QKV_WT  ((size_t)0)            // 3584 x 1152 x 2
#define OFF_PROJ_WT ((size_t)8257536)      // 1280 x 1152 x 2
#define OFF_FC1_WT  ((size_t)11206656)     // 4608 x 1152 x 2
#define OFF_FC2_WT  ((size_t)21823488)     // 1280 x 4608 x 2
#define OFF_H       ((size_t)33619968)     // 16384 x 1152 x 2
#define OFF_ATT     ((size_t)71368704)     // 16384 x 1152 x 2
#define OFF_Q       ((size_t)109117440)    // 256 x 1024 x 96 x 2
#define OFF_K       ((size_t)159449088)
#define OFF_VT      ((size_t)209780736)
#define OFF_HIDDEN  OFF_Q                  // aliases q/k/vt (dead by then)

// ---------------- weight transpose + cast: W[K][N] f32 -> Wt[N][K] bf16 ----------------
__global__ __launch_bounds__(256) void transpose_cast(
    const float* __restrict__ W, ushort_t* __restrict__ Wt, int K, int N)
{
    __shared__ float t[64][65];
    const int n0 = blockIdx.x * 64;
    const int k0 = blockIdx.y * 64;
    #pragma unroll
    for (int j = 0; j < 4; ++j) {
        int idx = threadIdx.x + j * 256;
        int r = idx >> 4;
        int c4 = idx & 15;
        float4 v = *(const float4*)&W[(size_t)(k0 + r) * N + n0 + c4 * 4];
        t[r][c4 * 4 + 0] = v.x; t[r][c4 * 4 + 1] = v.y;
        t[r][c4 * 4 + 2] = v.z; t[r][c4 * 4 + 3] = v.w;
    }
    __syncthreads();
    #pragma unroll
    for (int j = 0; j < 4; ++j) {
        int idx = threadIdx.x + j * 256;
        int rn = idx >> 4;
        int c4 = idx & 15;
        ushort4 o;
        o.x = f2bf(t[c4 * 4 + 0][rn]);
        o.y = f2bf(t[c4 * 4 + 1][rn]);
        o.z = f2bf(t[c4 * 4 + 2][rn]);
        o.w = f2bf(t[c4 * 4 + 3][rn]);
        *(ushort4*)&Wt[(size_t)(n0 + rn) * K + k0 + c4 * 4] = o;
    }
}

// ---------------- LayerNorm: f32 row(1152) -> bf16 ----------------
__global__ __launch_bounds__(256) void ln_kernel(
    const float* __restrict__ x, const float* __restrict__ g,
    const float* __restrict__ b, ushort_t* __restrict__ out)
{
    const int row = blockIdx.x;
    const int tid = threadIdx.x;
    const int lane = tid & 63, wid = tid >> 6;
    const float* xr = x + (size_t)row * Cdim;

    float4 v0 = ((const float4*)xr)[tid];
    float4 v1 = {0, 0, 0, 0};
    if (tid < 32) v1 = ((const float4*)xr)[256 + tid];
    float s  = v0.x + v0.y + v0.z + v0.w + v1.x + v1.y + v1.z + v1.w;
    float s2 = v0.x*v0.x + v0.y*v0.y + v0.z*v0.z + v0.w*v0.w
             + v1.x*v1.x + v1.y*v1.y + v1.z*v1.z + v1.w*v1.w;
    #pragma unroll
    for (int off = 32; off >= 1; off >>= 1) {
        s  += __shfl_xor(s, off);
        s2 += __shfl_xor(s2, off);
    }
    __shared__ float red[8];
    if (lane == 0) { red[wid] = s; red[4 + wid] = s2; }
    __syncthreads();
    s  = red[0] + red[1] + red[2] + red[3];
    s2 = red[4] + red[5] + red[6] + red[7];
    const float mu = s * (1.0f / Cdim);
    const float var = s2 * (1.0f / Cdim) - mu * mu;
    const float rs = rsqrtf(var + 1e-6f);

    ushort_t* orow = out + (size_t)row * Cdim;
    {
        float4 g4 = ((const float4*)g)[tid];
        float4 b4 = ((const float4*)b)[tid];
        ushort4 o;
        o.x = f2bf((v0.x - mu) * rs * g4.x + b4.x);
        o.y = f2bf((v0.y - mu) * rs * g4.y + b4.y);
        o.z = f2bf((v0.z - mu) * rs * g4.z + b4.z);
        o.w = f2bf((v0.w - mu) * rs * g4.w + b4.w);
        ((ushort4*)orow)[tid] = o;
    }
    if (tid < 32) {
        float4 g4 = ((const float4*)g)[256 + tid];
        float4 b4 = ((const float4*)b)[256 + tid];
        ushort4 o;
        o.x = f2bf((v1.x - mu) * rs * g4.x + b4.x);
        o.y = f2bf((v1.y - mu) * rs * g4.y + b4.y);
        o.z = f2bf((v1.z - mu) * rs * g4.z + b4.z);
        o.w = f2bf((v1.w - mu) * rs * g4.w + b4.w);
        ((ushort4*)orow)[256 + tid] = o;
    }
}

// ---------------- GEMM: persistent blocks, 256x128 tile, BK=64, ring-3 LDS ----------------
// (unchanged — proven: single barrier/K-step, vmcnt(6), 0 conflicts)
enum { EPI_QKV = 0, EPI_PROJ = 1, EPI_FC1 = 2, EPI_FC2 = 3 };

#define TBM 256
#define TBN 128
#define TBK 64
#define BUFB 49152   // bytes per ring buffer (A 32768 + B 16384)

template<int EPI, int N, int K>
__global__ __launch_bounds__(512, 1) void gemm_bt(
    const ushort_t* __restrict__ A, const ushort_t* __restrict__ Bt,
    const float* __restrict__ bias, const float* __restrict__ resid,
    float* __restrict__ outf, ushort_t* __restrict__ outb,
    ushort_t* __restrict__ outq, ushort_t* __restrict__ outk, ushort_t* __restrict__ outv)
{
    __shared__ ushort_t smem[3 * BUFB / 2];   // 144 KB
    const int tid = threadIdx.x;
    const int lane = tid & 63, wid = tid >> 6;
    const int wr = wid >> 1, wc = wid & 1;     // 4M x 2N waves, 64x64 out each
    const int fr = lane & 15, fq = lane >> 4;
    const int bid = blockIdx.x;
    constexpr int NTt = K / TBK;               // K-steps per tile
    constexpr int NTN = N / TBN;               // n-tiles
    constexpr int TT  = (Mrows / TBM) * NTN;   // total tiles (64 * NTN)

    size_t srcA[4]; int dstA[4];
    #pragma unroll
    for (int r = 0; r < 4; ++r) {
        const int chunk = r * 512 + tid;
        const int row = chunk >> 3, slot = chunk & 7;
        srcA[r] = (size_t)row * K + (slot ^ (row & 7)) * 8;
        dstA[r] = chunk * 16;
    }
    size_t srcB[2]; int dstB[2];
    #pragma unroll
    for (int r = 0; r < 2; ++r) {
        const int chunk = r * 512 + tid;
        const int row = chunk >> 3, slot = chunk & 7;
        srcB[r] = (size_t)row * K + (slot ^ (row & 7)) * 8;
        dstB[r] = 32768 + chunk * 16;
    }
    const int swz = (fr & 7) << 4;
    int aoff[4][2], boff[4][2];
    #pragma unroll
    for (int kh = 0; kh < 2; ++kh) {
        const int colb = (kh * 64 + fq * 16) ^ swz;
        #pragma unroll
        for (int i = 0; i < 4; ++i) {
            aoff[i][kh] = (wr * 64 + i * 16 + fr) * 128 + colb;
            boff[i][kh] = 32768 + (wc * 64 + i * 16 + fr) * 128 + colb;
        }
    }

    const int nj = (TT - bid + 255) / 256;
    const int total_u = nj * NTt;

    int js = 0, ts = 0, sbuf = 0;
    const ushort_t *sAb, *sBb;
    auto setbases = [&](int j) {
        int s = bid + j * 256; if (s >= TT) s = bid;
        const int mt = s & 63, nt = s >> 6;
        sAb = A + (size_t)(mt * TBM) * K;
        sBb = Bt + (size_t)(nt * TBN) * K;
    };
    setbases(0);
    auto STAGE = [&]() {
        char* lb = (char*)smem + (size_t)sbuf * BUFB;
        const ushort_t* Ab = sAb + ts * TBK;
        const ushort_t* Bb = sBb + ts * TBK;
        #pragma unroll
        for (int r = 0; r < 4; ++r) gld16(Ab + srcA[r], lb + dstA[r]);
        #pragma unroll
        for (int r = 0; r < 2; ++r) gld16(Bb + srcB[r], lb + dstB[r]);
        sbuf = (sbuf == 2) ? 0 : sbuf + 1;
        if (++ts == NTt) { ts = 0; setbases(++js); }
    };

    f32x4 acc[4][4] = {};
    STAGE(); STAGE();

    int jc = 0, tc = 0, cbuf = 0;
    for (int u = 0; u < total_u; ++u) {
        asm volatile("s_waitcnt vmcnt(6)" ::: "memory");
        __builtin_amdgcn_s_barrier();
        __builtin_amdgcn_sched_barrier(0);
        STAGE();
        __builtin_amdgcn_sched_barrier(0);
        const char* lb = (const char*)smem + (size_t)cbuf * BUFB;
        #pragma unroll
        for (int kh = 0; kh < 2; ++kh) {
            short8 a[4], b[4];
            #pragma unroll
            for (int i = 0; i < 4; ++i) {
                a[i] = *(const short8*)(lb + aoff[i][kh]);
                b[i] = *(const short8*)(lb + boff[i][kh]);
            }
            __builtin_amdgcn_s_setprio(1);
            #pragma unroll
            for (int mi = 0; mi < 4; ++mi)
                #pragma unroll
                for (int ni = 0; ni < 4; ++ni)
                    acc[mi][ni] = mfma16(a[mi], b[ni], acc[mi][ni]);
            __builtin_amdgcn_s_setprio(0);
        }
        cbuf = (cbuf == 2) ? 0 : cbuf + 1;

        if (++tc == NTt) {
            tc = 0;
            const int s = bid + jc * 256;
            const int m0 = (s & 63) * TBM, n0 = (s >> 6) * TBN;
            #pragma unroll
            for (int mi = 0; mi < 4; ++mi) {
                #pragma unroll
                for (int ni = 0; ni < 4; ++ni) {
                    const int col = n0 + wc * 64 + ni * 16 + fr;
                    const int rbase = m0 + wr * 64 + mi * 16 + fq * 4;
                    #pragma unroll
                    for (int i = 0; i < 4; ++i) {
                        const int r = rbase + i;
                        float v = acc[mi][ni][i];
                        if (EPI == EPI_QKV) {
                            v += bias[col];
                            const int which = col / Cdim;
                            const int rc = col % Cdim;
                            const int h = rc / Dh, d = rc % Dh;
                            const int b2 = r >> 10, n = r & 1023;
                            const size_t head = (size_t)(b2 * Hn + h);
                            if (which == 0)      outq[(head * Ntok + n) * Dp + d] = f2bf(v);
                            else if (which == 1) outk[(head * Ntok + n) * Dp + d] = f2bf(v);
                            else                 outv[(head * Dp + d) * Ntok + n] = f2bf(v);
                        } else if (EPI == EPI_PROJ) {
                            v += bias[col] + resid[(size_t)r * N + col];
                            outf[(size_t)r * N + col] = v;
                        } else if (EPI == EPI_FC1) {
                            v += bias[col];
                            v = 0.5f * v * (1.0f + erff(v * 0.70710678118f));
                            outb[(size_t)r * N + col] = f2bf(v);
                        } else { // EPI_FC2
                            v += bias[col] + outf[(size_t)r * N + col];
                            outf[(size_t)r * N + col] = v;
                        }
                        acc[mi][ni][i] = 0.0f;
                    }
                }
            }
            ++jc;
        }
    }
}

// ---------------- flash attention: XCD-local + no-max softmax + reg pipeline ----------------
// 2x-unrolled KV loop with ping-pong K registers: K(t+1) issued a half-iteration
// before use (covered by ~700cy of compute); V issued at the half's top (covered
// by QK+softmax). QK never waits on a fresh global load.
// plds rows padded to 40 ushorts (80B): b128 read's 8-lane groups tile all 32
// banks ({0,20,8,28,16,4,24,12} dword starts) -> conflict-free bounce.
__global__ __launch_bounds__(256) void attn_kernel(
    const ushort_t* __restrict__ q, const ushort_t* __restrict__ k,
    const ushort_t* __restrict__ vt, ushort_t* __restrict__ out)
{
    const int tid = threadIdx.x;
    const int lane = tid & 63, wid = tid >> 6;
    const int bid = blockIdx.x;
    const int xcd = bid & 7;
    const int bh = (bid >> 6) * 8 + xcd;
    const int qblk = (bid >> 3) & 7;
    const int qbase = qblk * 128 + wid * 32;
    const int fr = lane & 15, fq = lane >> 4;
    const ushort_t* qh = q  + (size_t)bh * Ntok * Dp;
    const ushort_t* kh = k  + (size_t)bh * Ntok * Dp;
    const ushort_t* vh = vt + (size_t)bh * Dp * Ntok;

    short8 aq[2][3];
    #pragma unroll
    for (int t = 0; t < 2; ++t)
        #pragma unroll
        for (int ks = 0; ks < 3; ++ks)
            aq[t][ks] = *(const short8*)&qh[(size_t)(qbase + t * 16 + fr) * Dp + ks * 32 + fq * 8];

    f32x4 o[2][5] = {};
    float lsum[2][4] = {};

    __shared__ ushort_t plds[4][2][16][40];   // row stride 80B: conflict-free
    const float scale = 0.117851130f;   // 72^-0.5

    short8 kA0[3], kA1[3], kB0[3], kB1[3], v0[5], v1[5];
    #pragma unroll
    for (int ks = 0; ks < 3; ++ks) {
        kA0[ks] = *(const short8*)&kh[(size_t)(fr) * Dp + ks * 32 + fq * 8];
        kA1[ks] = *(const short8*)&kh[(size_t)(16 + fr) * Dp + ks * 32 + fq * 8];
    }

    #define ATTN_HALF(KB0, KB1, VV, KVOFF)                                            \
    {                                                                                 \
        f32x4 s[2][2] = {};                                                           \
        __builtin_amdgcn_s_setprio(1);                                                \
        _Pragma("unroll")                                                             \
        for (int ks = 0; ks < 3; ++ks)                                                \
            _Pragma("unroll")                                                         \
            for (int t = 0; t < 2; ++t) {                                             \
                s[t][0] = mfma16(aq[t][ks], KB0[ks], s[t][0]);                        \
                s[t][1] = mfma16(aq[t][ks], KB1[ks], s[t][1]);                        \
            }                                                                         \
        __builtin_amdgcn_s_setprio(0);                                                \
        _Pragma("unroll")                                                             \
        for (int t = 0; t < 2; ++t) {                                                 \
            _Pragma("unroll")                                                         \
            for (int i = 0; i < 4; ++i) {                                             \
                float p0 = __expf(s[t][0][i] * scale);                                \
                float p1 = __expf(s[t][1][i] * scale);                                \
                lsum[t][i] += p0 + p1;                                                \
                plds[wid][t][fq * 4 + i][fr]      = f2bf(p0);                         \
                plds[wid][t][fq * 4 + i][16 + fr] = f2bf(p1);                         \
            }                                                                         \
        }                                                                             \
        short8 pa[2];                                                                 \
        _Pragma("unroll")                                                             \
        for (int t = 0; t < 2; ++t)                                                   \
            pa[t] = *(const short8*)&plds[wid][t][fr][fq * 8];                        \
        __builtin_amdgcn_s_setprio(1);                                                \
        _Pragma("unroll")                                                             \
        for (int dt = 0; dt < 5; ++dt)                                                \
            _Pragma("unroll")                                                         \
            for (int t = 0; t < 2; ++t)                                               \
                o[t][dt] = mfma16(pa[t], VV[dt], o[t][dt]);                           \
        __builtin_amdgcn_s_setprio(0);                                                \
    }

    for (int kv = 0; kv < Ntok; kv += 64) {
        // ---- half A: tile kv (K in kA, prefetch kB for kv+32, V0 at top)
        #pragma unroll
        for (int dt = 0; dt < 5; ++dt)
            v0[dt] = *(const short8*)&vh[(size_t)(dt * 16 + fr) * Ntok + kv + fq * 8];
        #pragma unroll
        for (int ks = 0; ks < 3; ++ks) {
            kB0[ks] = *(const short8*)&kh[(size_t)(kv + 32 + fr) * Dp + ks * 32 + fq * 8];
            kB1[ks] = *(const short8*)&kh[(size_t)(kv + 48 + fr) * Dp + ks * 32 + fq * 8];
        }
        ATTN_HALF(kA0, kA1, v0, kv)

        // ---- half B: tile kv+32 (K in kB, prefetch kA for kv+64, V1 at top)
        #pragma unroll
        for (int dt = 0; dt < 5; ++dt)
            v1[dt] = *(const short8*)&vh[(size_t)(dt * 16 + fr) * Ntok + kv + 32 + fq * 8];
        if (kv + 64 < Ntok) {
            #pragma unroll
            for (int ks = 0; ks < 3; ++ks) {
                kA0[ks] = *(const short8*)&kh[(size_t)(kv + 64 + fr) * Dp + ks * 32 + fq * 8];
                kA1[ks] = *(const short8*)&kh[(size_t)(kv + 80 + fr) * Dp + ks * 32 + fq * 8];
            }
        }
        ATTN_HALF(kB0, kB1, v1, kv + 32)
    }
    #undef ATTN_HALF

    const int b = bh >> 4, h = bh & 15;
    #pragma unroll
    for (int t = 0; t < 2; ++t) {
        float inv[4];
        #pragma unroll
        for (int i = 0; i < 4; ++i) {
            float s = lsum[t][i];
            s += __shfl_xor(s, 1);
            s += __shfl_xor(s, 2);
            s += __shfl_xor(s, 4);
            s += __shfl_xor(s, 8);
            inv[i] = 1.0f / s;
        }
        #pragma unroll
        for (int dt = 0; dt < 5; ++dt) {
            const int d = dt * 16 + fr;
            if (d < Dh) {
                #pragma unroll
                for (int i = 0; i < 4; ++i) {
                    const size_t idx = ((size_t)(b * Ntok) + qbase + t * 16 + fq * 4 + i) * Cdim + h * Dh + d;
                    out[idx] = f2bf(o[t][dt][i] * inv[i]);
                }
            }
        }
    }
}

// ---------------- launch ----------------
extern "C" void kernel_launch(void* const* d_in, const int* in_sizes, int n_in,
                              void* d_out, int out_size, void* d_ws, size_t ws_size,
                              hipStream_t stream) {
    const float* x      = (const float*)d_in[0];
    const float* ln1_g  = (const float*)d_in[1];
    const float* ln1_b  = (const float*)d_in[2];
    const float* qkv_w  = (const float*)d_in[3];
    const float* qkv_b  = (const float*)d_in[4];
    const float* proj_w = (const float*)d_in[5];
    const float* proj_b = (const float*)d_in[6];
    const float* ln2_g  = (const float*)d_in[7];
    const float* ln2_b  = (const float*)d_in[8];
    const float* fc1_w  = (const float*)d_in[9];
    const float* fc1_b  = (const float*)d_in[10];
    const float* fc2_w  = (const float*)d_in[11];
    const float* fc2_b  = (const float*)d_in[12];

    char* ws = (char*)d_ws;
    ushort_t* qkv_wT  = (ushort_t*)(ws + OFF_QKV_WT);
    ushort_t* proj_wT = (ushort_t*)(ws + OFF_PROJ_WT);
    ushort_t* fc1_wT  = (ushort_t*)(ws + OFF_FC1_WT);
    ushort_t* fc2_wT  = (ushort_t*)(ws + OFF_FC2_WT);
    ushort_t* hbuf    = (ushort_t*)(ws + OFF_H);
    ushort_t* attnout = (ushort_t*)(ws + OFF_ATT);
    ushort_t* qb      = (ushort_t*)(ws + OFF_Q);
    ushort_t* kb      = (ushort_t*)(ws + OFF_K);
    ushort_t* vtb     = (ushort_t*)(ws + OFF_VT);
    ushort_t* hidden  = (ushort_t*)(ws + OFF_HIDDEN);
    float* out = (float*)d_out;

    // zero q/k/vt (covers the D=72..95 padding the MFMA K-loop reads)
    hipMemsetAsync(ws + OFF_Q, 0, (size_t)3 * 50331648, stream);

    transpose_cast<<<dim3(3 * Cdim / 64, Cdim / 64), 256, 0, stream>>>(qkv_w, qkv_wT, Cdim, 3 * Cdim);
    transpose_cast<<<dim3(Cdim / 64, Cdim / 64), 256, 0, stream>>>(proj_w, proj_wT, Cdim, Cdim);
    transpose_cast<<<dim3(INNER / 64, Cdim / 64), 256, 0, stream>>>(fc1_w, fc1_wT, Cdim, INNER);
    transpose_cast<<<dim3(Cdim / 64, INNER / 64), 256, 0, stream>>>(fc2_w, fc2_wT, INNER, Cdim);

    ln_kernel<<<Mrows, 256, 0, stream>>>(x, ln1_g, ln1_b, hbuf);

    gemm_bt<EPI_QKV, 3 * Cdim, Cdim><<<256, 512, 0, stream>>>(
        hbuf, qkv_wT, qkv_b, nullptr, nullptr, nullptr, qb, kb, vtb);

    attn_kernel<<<2048, 256, 0, stream>>>(qb, kb, vtb, attnout);

    gemm_bt<EPI_PROJ, Cdim, Cdim><<<256, 512, 0, stream>>>(
        attnout, proj_wT, proj_b, x, out, nullptr, nullptr, nullptr, nullptr);

    ln_kernel<<<Mrows, 256, 0, stream>>>(out, ln2_g, ln2_b, hbuf);

    gemm_bt<EPI_FC1, INNER, Cdim><<<256, 512, 0, stream>>>(
        hbuf, fc1_wT, fc1_b, nullptr, nullptr, hidden, nullptr, nullptr, nullptr);

    gemm_bt<EPI_FC2, Cdim, INNER><<<256, 512, 0, stream>>>(
        hidden, fc2_wT, fc2_b, nullptr, out, nullptr, nullptr, nullptr, nullptr);
}

// Round 15
// 1053.924 us; speedup vs baseline: 1.0058x; 1.0058x over previous
//
#include <hip/hip_runtime.h>
#include <hip/hip_bf16.h>

typedef unsigned short ushort_t;
using short8 = __attribute__((ext_vector_type(8))) short;
using f32x4  = __attribute__((ext_vector_type(4))) float;

#define DEVI __device__ __forceinline__

DEVI ushort_t f2bf(float f) {
    union { float f; unsigned u; } c; c.f = f;
    unsigned u = c.u;
    return (ushort_t)((u + 0x7FFF + ((u >> 16) & 1)) >> 16);
}

DEVI f32x4 mfma16(short8 a, short8 b, f32x4 c) {
    return __builtin_amdgcn_mfma_f32_16x16x32_bf16(a, b, c, 0, 0, 0);
}

DEVI void gld16(const void* g, void* l) {
    __builtin_amdgcn_global_load_lds(
        (const __attribute__((address_space(1))) unsigned int*)g,
        (__attribute__((address_space(3))) unsigned int*)l, 16, 0, 0);
}

// ---------------- constants ----------------
#define Bsz 16
#define Ntok 1024
#define Cdim 1152
#define Hn 16
#define Dh 72
#define Dp 96
#define INNER 4608
#define Mrows (Bsz * Ntok)   // 16384

// workspace offsets (bytes)
#define OFF_QKV_WT  ((size_t)0)            // 3584 x 1152 x 2
#define OFF_PROJ_WT ((size_t)8257536)      // 1280 x 1152 x 2
#define OFF_FC1_WT  ((size_t)11206656)     // 4608 x 1152 x 2
#define OFF_FC2_WT  ((size_t)21823488)     // 1280 x 4608 x 2
#define OFF_H       ((size_t)33619968)     // 16384 x 1152 x 2
#define OFF_ATT     ((size_t)71368704)     // 16384 x 1152 x 2
#define OFF_Q       ((size_t)109117440)    // 256 x 1024 x 96 x 2
#define OFF_K       ((size_t)159449088)
#define OFF_VT      ((size_t)209780736)
#define OFF_HIDDEN  OFF_Q                  // aliases q/k/vt (dead by then)

// ---------------- weight transpose + cast: W[K][N] f32 -> Wt[N][K] bf16 ----------------
__global__ __launch_bounds__(256) void transpose_cast(
    const float* __restrict__ W, ushort_t* __restrict__ Wt, int K, int N)
{
    __shared__ float t[64][65];
    const int n0 = blockIdx.x * 64;
    const int k0 = blockIdx.y * 64;
    #pragma unroll
    for (int j = 0; j < 4; ++j) {
        int idx = threadIdx.x + j * 256;
        int r = idx >> 4;
        int c4 = idx & 15;
        float4 v = *(const float4*)&W[(size_t)(k0 + r) * N + n0 + c4 * 4];
        t[r][c4 * 4 + 0] = v.x; t[r][c4 * 4 + 1] = v.y;
        t[r][c4 * 4 + 2] = v.z; t[r][c4 * 4 + 3] = v.w;
    }
    __syncthreads();
    #pragma unroll
    for (int j = 0; j < 4; ++j) {
        int idx = threadIdx.x + j * 256;
        int rn = idx >> 4;
        int c4 = idx & 15;
        ushort4 o;
        o.x = f2bf(t[c4 * 4 + 0][rn]);
        o.y = f2bf(t[c4 * 4 + 1][rn]);
        o.z = f2bf(t[c4 * 4 + 2][rn]);
        o.w = f2bf(t[c4 * 4 + 3][rn]);
        *(ushort4*)&Wt[(size_t)(n0 + rn) * K + k0 + c4 * 4] = o;
    }
}

// ---------------- LayerNorm: f32 row(1152) -> bf16 ----------------
__global__ __launch_bounds__(256) void ln_kernel(
    const float* __restrict__ x, const float* __restrict__ g,
    const float* __restrict__ b, ushort_t* __restrict__ out)
{
    const int row = blockIdx.x;
    const int tid = threadIdx.x;
    const int lane = tid & 63, wid = tid >> 6;
    const float* xr = x + (size_t)row * Cdim;

    float4 v0 = ((const float4*)xr)[tid];
    float4 v1 = {0, 0, 0, 0};
    if (tid < 32) v1 = ((const float4*)xr)[256 + tid];
    float s  = v0.x + v0.y + v0.z + v0.w + v1.x + v1.y + v1.z + v1.w;
    float s2 = v0.x*v0.x + v0.y*v0.y + v0.z*v0.z + v0.w*v0.w
             + v1.x*v1.x + v1.y*v1.y + v1.z*v1.z + v1.w*v1.w;
    #pragma unroll
    for (int off = 32; off >= 1; off >>= 1) {
        s  += __shfl_xor(s, off);
        s2 += __shfl_xor(s2, off);
    }
    __shared__ float red[8];
    if (lane == 0) { red[wid] = s; red[4 + wid] = s2; }
    __syncthreads();
    s  = red[0] + red[1] + red[2] + red[3];
    s2 = red[4] + red[5] + red[6] + red[7];
    const float mu = s * (1.0f / Cdim);
    const float var = s2 * (1.0f / Cdim) - mu * mu;
    const float rs = rsqrtf(var + 1e-6f);

    ushort_t* orow = out + (size_t)row * Cdim;
    {
        float4 g4 = ((const float4*)g)[tid];
        float4 b4 = ((const float4*)b)[tid];
        ushort4 o;
        o.x = f2bf((v0.x - mu) * rs * g4.x + b4.x);
        o.y = f2bf((v0.y - mu) * rs * g4.y + b4.y);
        o.z = f2bf((v0.z - mu) * rs * g4.z + b4.z);
        o.w = f2bf((v0.w - mu) * rs * g4.w + b4.w);
        ((ushort4*)orow)[tid] = o;
    }
    if (tid < 32) {
        float4 g4 = ((const float4*)g)[256 + tid];
        float4 b4 = ((const float4*)b)[256 + tid];
        ushort4 o;
        o.x = f2bf((v1.x - mu) * rs * g4.x + b4.x);
        o.y = f2bf((v1.y - mu) * rs * g4.y + b4.y);
        o.z = f2bf((v1.z - mu) * rs * g4.z + b4.z);
        o.w = f2bf((v1.w - mu) * rs * g4.w + b4.w);
        ((ushort4*)orow)[256 + tid] = o;
    }
}

// ---------------- GEMM: persistent blocks, 256x128 tile, BK=64, ring-3 LDS ----------------
// (unchanged — proven: single barrier/K-step, vmcnt(6), 0 conflicts)
enum { EPI_QKV = 0, EPI_PROJ = 1, EPI_FC1 = 2, EPI_FC2 = 3 };

#define TBM 256
#define TBN 128
#define TBK 64
#define BUFB 49152   // bytes per ring buffer (A 32768 + B 16384)

template<int EPI, int N, int K>
__global__ __launch_bounds__(512, 1) void gemm_bt(
    const ushort_t* __restrict__ A, const ushort_t* __restrict__ Bt,
    const float* __restrict__ bias, const float* __restrict__ resid,
    float* __restrict__ outf, ushort_t* __restrict__ outb,
    ushort_t* __restrict__ outq, ushort_t* __restrict__ outk, ushort_t* __restrict__ outv)
{
    __shared__ ushort_t smem[3 * BUFB / 2];   // 144 KB
    const int tid = threadIdx.x;
    const int lane = tid & 63, wid = tid >> 6;
    const int wr = wid >> 1, wc = wid & 1;     // 4M x 2N waves, 64x64 out each
    const int fr = lane & 15, fq = lane >> 4;
    const int bid = blockIdx.x;
    constexpr int NTt = K / TBK;               // K-steps per tile
    constexpr int NTN = N / TBN;               // n-tiles
    constexpr int TT  = (Mrows / TBM) * NTN;   // total tiles (64 * NTN)

    size_t srcA[4]; int dstA[4];
    #pragma unroll
    for (int r = 0; r < 4; ++r) {
        const int chunk = r * 512 + tid;
        const int row = chunk >> 3, slot = chunk & 7;
        srcA[r] = (size_t)row * K + (slot ^ (row & 7)) * 8;
        dstA[r] = chunk * 16;
    }
    size_t srcB[2]; int dstB[2];
    #pragma unroll
    for (int r = 0; r < 2; ++r) {
        const int chunk = r * 512 + tid;
        const int row = chunk >> 3, slot = chunk & 7;
        srcB[r] = (size_t)row * K + (slot ^ (row & 7)) * 8;
        dstB[r] = 32768 + chunk * 16;
    }
    const int swz = (fr & 7) << 4;
    int aoff[4][2], boff[4][2];
    #pragma unroll
    for (int kh = 0; kh < 2; ++kh) {
        const int colb = (kh * 64 + fq * 16) ^ swz;
        #pragma unroll
        for (int i = 0; i < 4; ++i) {
            aoff[i][kh] = (wr * 64 + i * 16 + fr) * 128 + colb;
            boff[i][kh] = 32768 + (wc * 64 + i * 16 + fr) * 128 + colb;
        }
    }

    const int nj = (TT - bid + 255) / 256;
    const int total_u = nj * NTt;

    int js = 0, ts = 0, sbuf = 0;
    const ushort_t *sAb, *sBb;
    auto setbases = [&](int j) {
        int s = bid + j * 256; if (s >= TT) s = bid;
        const int mt = s & 63, nt = s >> 6;
        sAb = A + (size_t)(mt * TBM) * K;
        sBb = Bt + (size_t)(nt * TBN) * K;
    };
    setbases(0);
    auto STAGE = [&]() {
        char* lb = (char*)smem + (size_t)sbuf * BUFB;
        const ushort_t* Ab = sAb + ts * TBK;
        const ushort_t* Bb = sBb + ts * TBK;
        #pragma unroll
        for (int r = 0; r < 4; ++r) gld16(Ab + srcA[r], lb + dstA[r]);
        #pragma unroll
        for (int r = 0; r < 2; ++r) gld16(Bb + srcB[r], lb + dstB[r]);
        sbuf = (sbuf == 2) ? 0 : sbuf + 1;
        if (++ts == NTt) { ts = 0; setbases(++js); }
    };

    f32x4 acc[4][4] = {};
    STAGE(); STAGE();

    int jc = 0, tc = 0, cbuf = 0;
    for (int u = 0; u < total_u; ++u) {
        asm volatile("s_waitcnt vmcnt(6)" ::: "memory");
        __builtin_amdgcn_s_barrier();
        __builtin_amdgcn_sched_barrier(0);
        STAGE();
        __builtin_amdgcn_sched_barrier(0);
        const char* lb = (const char*)smem + (size_t)cbuf * BUFB;
        #pragma unroll
        for (int kh = 0; kh < 2; ++kh) {
            short8 a[4], b[4];
            #pragma unroll
            for (int i = 0; i < 4; ++i) {
                a[i] = *(const short8*)(lb + aoff[i][kh]);
                b[i] = *(const short8*)(lb + boff[i][kh]);
            }
            __builtin_amdgcn_s_setprio(1);
            #pragma unroll
            for (int mi = 0; mi < 4; ++mi)
                #pragma unroll
                for (int ni = 0; ni < 4; ++ni)
                    acc[mi][ni] = mfma16(a[mi], b[ni], acc[mi][ni]);
            __builtin_amdgcn_s_setprio(0);
        }
        cbuf = (cbuf == 2) ? 0 : cbuf + 1;

        if (++tc == NTt) {
            tc = 0;
            const int s = bid + jc * 256;
            const int m0 = (s & 63) * TBM, n0 = (s >> 6) * TBN;
            #pragma unroll
            for (int mi = 0; mi < 4; ++mi) {
                #pragma unroll
                for (int ni = 0; ni < 4; ++ni) {
                    const int col = n0 + wc * 64 + ni * 16 + fr;
                    const int rbase = m0 + wr * 64 + mi * 16 + fq * 4;
                    #pragma unroll
                    for (int i = 0; i < 4; ++i) {
                        const int r = rbase + i;
                        float v = acc[mi][ni][i];
                        if (EPI == EPI_QKV) {
                            v += bias[col];
                            const int which = col / Cdim;
                            const int rc = col % Cdim;
                            const int h = rc / Dh, d = rc % Dh;
                            const int b2 = r >> 10, n = r & 1023;
                            const size_t head = (size_t)(b2 * Hn + h);
                            if (which == 0)      outq[(head * Ntok + n) * Dp + d] = f2bf(v);
                            else if (which == 1) outk[(head * Ntok + n) * Dp + d] = f2bf(v);
                            else                 outv[(head * Dp + d) * Ntok + n] = f2bf(v);
                        } else if (EPI == EPI_PROJ) {
                            v += bias[col] + resid[(size_t)r * N + col];
                            outf[(size_t)r * N + col] = v;
                        } else if (EPI == EPI_FC1) {
                            v += bias[col];
                            v = 0.5f * v * (1.0f + erff(v * 0.70710678118f));
                            outb[(size_t)r * N + col] = f2bf(v);
                        } else { // EPI_FC2
                            v += bias[col] + outf[(size_t)r * N + col];
                            outf[(size_t)r * N + col] = v;
                        }
                        acc[mi][ni][i] = 0.0f;
                    }
                }
            }
            ++jc;
        }
    }
}

// ---------------- flash attention: swapped-QK^T + cvt_pk + wide LDS bounce ----------------
// Theory: previous structure issued 18 LDS ops per half (16 scattered b16 P-writes
// + 2 b128 reads); 16 waves/CU saturate the LDS pipe by op COUNT. Swapped QK
// (s = mfma(K, Q), same operand loads) makes each lane hold P[q=fr] with
// CONTIGUOUS k-runs {4fq..4fq+3} and {16+4fq..}, packed by v_cvt_pk_bf16_f32
// (1 op / 2 values) and stored as 2x ds_write_b64 per tile; PA read = 1x b128.
// LDS ops per half: 18 -> 6. lsum is lane-scalar (q=fr), reduced shfl_xor(16,32),
// redistributed to q=fq*4+i by 4 shfls at the end.
__global__ __launch_bounds__(256) void attn_kernel(
    const ushort_t* __restrict__ q, const ushort_t* __restrict__ k,
    const ushort_t* __restrict__ vt, ushort_t* __restrict__ out)
{
    const int tid = threadIdx.x;
    const int lane = tid & 63, wid = tid >> 6;
    const int bid = blockIdx.x;
    const int xcd = bid & 7;
    const int bh = (bid >> 6) * 8 + xcd;
    const int qblk = (bid >> 3) & 7;
    const int qbase = qblk * 128 + wid * 32;
    const int fr = lane & 15, fq = lane >> 4;
    const ushort_t* qh = q  + (size_t)bh * Ntok * Dp;
    const ushort_t* kh = k  + (size_t)bh * Ntok * Dp;
    const ushort_t* vh = vt + (size_t)bh * Dp * Ntok;

    short8 aq[2][3];
    #pragma unroll
    for (int t = 0; t < 2; ++t)
        #pragma unroll
        for (int ks = 0; ks < 3; ++ks)
            aq[t][ks] = *(const short8*)&qh[(size_t)(qbase + t * 16 + fr) * Dp + ks * 32 + fq * 8];

    f32x4 o[2][5] = {};
    float lsum[2] = {0.0f, 0.0f};   // per-lane: q = fr, partial over this lane's 8 k's

    __shared__ ushort_t plds[4][2][16][40];   // row stride 80B (16B-aligned reads)
    const float scale = 0.117851130f;   // 72^-0.5

    short8 kA0[3], kA1[3], kB0[3], kB1[3], v0[5], v1[5];
    #pragma unroll
    for (int ks = 0; ks < 3; ++ks) {
        kA0[ks] = *(const short8*)&kh[(size_t)(fr) * Dp + ks * 32 + fq * 8];
        kA1[ks] = *(const short8*)&kh[(size_t)(16 + fr) * Dp + ks * 32 + fq * 8];
    }

    #define ATTN_HALF(KB0, KB1, VV)                                                   \
    {                                                                                 \
        f32x4 s[2][2] = {};                                                           \
        __builtin_amdgcn_s_setprio(1);                                                \
        _Pragma("unroll")                                                             \
        for (int t = 0; t < 2; ++t)                                                   \
            _Pragma("unroll")                                                         \
            for (int ks = 0; ks < 3; ++ks) {                                          \
                s[t][0] = mfma16(KB0[ks], aq[t][ks], s[t][0]);                        \
                s[t][1] = mfma16(KB1[ks], aq[t][ks], s[t][1]);                        \
            }                                                                         \
        __builtin_amdgcn_s_setprio(0);                                                \
        _Pragma("unroll")                                                             \
        for (int t = 0; t < 2; ++t) {                                                 \
            float e0[4], e1[4];                                                       \
            _Pragma("unroll")                                                         \
            for (int i = 0; i < 4; ++i) {                                             \
                e0[i] = __expf(s[t][0][i] * scale);                                   \
                e1[i] = __expf(s[t][1][i] * scale);                                   \
            }                                                                         \
            lsum[t] += e0[0] + e0[1] + e0[2] + e0[3]                                  \
                     + e1[0] + e1[1] + e1[2] + e1[3];                                 \
            unsigned w0, w1, w2, w3;                                                  \
            asm("v_cvt_pk_bf16_f32 %0, %1, %2" : "=v"(w0) : "v"(e0[0]), "v"(e0[1])); \
            asm("v_cvt_pk_bf16_f32 %0, %1, %2" : "=v"(w1) : "v"(e0[2]), "v"(e0[3])); \
            asm("v_cvt_pk_bf16_f32 %0, %1, %2" : "=v"(w2) : "v"(e1[0]), "v"(e1[1])); \
            asm("v_cvt_pk_bf16_f32 %0, %1, %2" : "=v"(w3) : "v"(e1[2]), "v"(e1[3])); \
            uint2 lo; lo.x = w0; lo.y = w1;                                           \
            uint2 hi; hi.x = w2; hi.y = w3;                                           \
            *(uint2*)&plds[wid][t][fr][4 * fq]      = lo;                             \
            *(uint2*)&plds[wid][t][fr][16 + 4 * fq] = hi;                             \
        }                                                                             \
        short8 pa[2];                                                                 \
        _Pragma("unroll")                                                             \
        for (int t = 0; t < 2; ++t)                                                   \
            pa[t] = *(const short8*)&plds[wid][t][fr][8 * fq];                        \
        __builtin_amdgcn_s_setprio(1);                                                \
        _Pragma("unroll")                                                             \
        for (int dt = 0; dt < 5; ++dt)                                                \
            _Pragma("unroll")                                                         \
            for (int t = 0; t < 2; ++t)                                               \
                o[t][dt] = mfma16(pa[t], VV[dt], o[t][dt]);                           \
        __builtin_amdgcn_s_setprio(0);                                                \
    }

    for (int kv = 0; kv < Ntok; kv += 64) {
        // ---- half A: tile kv (K in kA, prefetch kB for kv+32, V0 at top)
        #pragma unroll
        for (int dt = 0; dt < 5; ++dt)
            v0[dt] = *(const short8*)&vh[(size_t)(dt * 16 + fr) * Ntok + kv + fq * 8];
        #pragma unroll
        for (int ks = 0; ks < 3; ++ks) {
            kB0[ks] = *(const short8*)&kh[(size_t)(kv + 32 + fr) * Dp + ks * 32 + fq * 8];
            kB1[ks] = *(const short8*)&kh[(size_t)(kv + 48 + fr) * Dp + ks * 32 + fq * 8];
        }
        ATTN_HALF(kA0, kA1, v0)

        // ---- half B: tile kv+32 (K in kB, prefetch kA for kv+64, V1 at top)
        #pragma unroll
        for (int dt = 0; dt < 5; ++dt)
            v1[dt] = *(const short8*)&vh[(size_t)(dt * 16 + fr) * Ntok + kv + 32 + fq * 8];
        if (kv + 64 < Ntok) {
            #pragma unroll
            for (int ks = 0; ks < 3; ++ks) {
                kA0[ks] = *(const short8*)&kh[(size_t)(kv + 64 + fr) * Dp + ks * 32 + fq * 8];
                kA1[ks] = *(const short8*)&kh[(size_t)(kv + 80 + fr) * Dp + ks * 32 + fq * 8];
            }
        }
        ATTN_HALF(kB0, kB1, v1)
    }
    #undef ATTN_HALF

    // reduce lsum over the k-distribution (fq = lane bits 4,5); all lanes end
    // with the full row-sum for q = fr.
    float Lred[2];
    #pragma unroll
    for (int t = 0; t < 2; ++t) {
        float s = lsum[t];
        s += __shfl_xor(s, 16);
        s += __shfl_xor(s, 32);
        Lred[t] = s;
    }

    const int b = bh >> 4, h = bh & 15;
    #pragma unroll
    for (int t = 0; t < 2; ++t) {
        float inv[4];
        #pragma unroll
        for (int i = 0; i < 4; ++i)
            inv[i] = 1.0f / __shfl(Lred[t], fq * 4 + i);   // q = fq*4+i held at lane fr==q
        #pragma unroll
        for (int dt = 0; dt < 5; ++dt) {
            const int d = dt * 16 + fr;
            if (d < Dh) {
                #pragma unroll
                for (int i = 0; i < 4; ++i) {
                    const size_t idx = ((size_t)(b * Ntok) + qbase + t * 16 + fq * 4 + i) * Cdim + h * Dh + d;
                    out[idx] = f2bf(o[t][dt][i] * inv[i]);
                }
            }
        }
    }
}

// ---------------- launch ----------------
extern "C" void kernel_launch(void* const* d_in, const int* in_sizes, int n_in,
                              void* d_out, int out_size, void* d_ws, size_t ws_size,
                              hipStream_t stream) {
    const float* x      = (const float*)d_in[0];
    const float* ln1_g  = (const float*)d_in[1];
    const float* ln1_b  = (const float*)d_in[2];
    const float* qkv_w  = (const float*)d_in[3];
    const float* qkv_b  = (const float*)d_in[4];
    const float* proj_w = (const float*)d_in[5];
    const float* proj_b = (const float*)d_in[6];
    const float* ln2_g  = (const float*)d_in[7];
    const float* ln2_b  = (const float*)d_in[8];
    const float* fc1_w  = (const float*)d_in[9];
    const float* fc1_b  = (const float*)d_in[10];
    const float* fc2_w  = (const float*)d_in[11];
    const float* fc2_b  = (const float*)d_in[12];

    char* ws = (char*)d_ws;
    ushort_t* qkv_wT  = (ushort_t*)(ws + OFF_QKV_WT);
    ushort_t* proj_wT = (ushort_t*)(ws + OFF_PROJ_WT);
    ushort_t* fc1_wT  = (ushort_t*)(ws + OFF_FC1_WT);
    ushort_t* fc2_wT  = (ushort_t*)(ws + OFF_FC2_WT);
    ushort_t* hbuf    = (ushort_t*)(ws + OFF_H);
    ushort_t* attnout = (ushort_t*)(ws + OFF_ATT);
    ushort_t* qb      = (ushort_t*)(ws + OFF_Q);
    ushort_t* kb      = (ushort_t*)(ws + OFF_K);
    ushort_t* vtb     = (ushort_t*)(ws + OFF_VT);
    ushort_t* hidden  = (ushort_t*)(ws + OFF_HIDDEN);
    float* out = (float*)d_out;

    // zero q/k/vt (covers the D=72..95 padding the MFMA K-loop reads)
    hipMemsetAsync(ws + OFF_Q, 0, (size_t)3 * 50331648, stream);

    transpose_cast<<<dim3(3 * Cdim / 64, Cdim / 64), 256, 0, stream>>>(qkv_w, qkv_wT, Cdim, 3 * Cdim);
    transpose_cast<<<dim3(Cdim / 64, Cdim / 64), 256, 0, stream>>>(proj_w, proj_wT, Cdim, Cdim);
    transpose_cast<<<dim3(INNER / 64, Cdim / 64), 256, 0, stream>>>(fc1_w, fc1_wT, Cdim, INNER);
    transpose_cast<<<dim3(Cdim / 64, INNER / 64), 256, 0, stream>>>(fc2_w, fc2_wT, INNER, Cdim);

    ln_kernel<<<Mrows, 256, 0, stream>>>(x, ln1_g, ln1_b, hbuf);

    gemm_bt<EPI_QKV, 3 * Cdim, Cdim><<<256, 512, 0, stream>>>(
        hbuf, qkv_wT, qkv_b, nullptr, nullptr, nullptr, qb, kb, vtb);

    attn_kernel<<<2048, 256, 0, stream>>>(qb, kb, vtb, attnout);

    gemm_bt<EPI_PROJ, Cdim, Cdim><<<256, 512, 0, stream>>>(
        attnout, proj_wT, proj_b, x, out, nullptr, nullptr, nullptr, nullptr);

    ln_kernel<<<Mrows, 256, 0, stream>>>(out, ln2_g, ln2_b, hbuf);

    gemm_bt<EPI_FC1, INNER, Cdim><<<256, 512, 0, stream>>>(
        hbuf, fc1_wT, fc1_b, nullptr, nullptr, hidden, nullptr, nullptr, nullptr);

    gemm_bt<EPI_FC2, Cdim, INNER><<<256, 512, 0, stream>>>(
        hidden, fc2_wT, fc2_b, nullptr, out, nullptr, nullptr, nullptr, nullptr);
}

// Round 17
// 1039.448 us; speedup vs baseline: 1.0198x; 1.0139x over previous
//
#include <hip/hip_runtime.h>
#include <hip/hip_bf16.h>

typedef unsigned short ushort_t;
using short8 = __attribute__((ext_vector_type(8))) short;
using f32x4  = __attribute__((ext_vector_type(4))) float;

#define DEVI __device__ __forceinline__

DEVI ushort_t f2bf(float f) {
    union { float f; unsigned u; } c; c.f = f;
    unsigned u = c.u;
    return (ushort_t)((u + 0x7FFF + ((u >> 16) & 1)) >> 16);
}

DEVI f32x4 mfma16(short8 a, short8 b, f32x4 c) {
    return __builtin_amdgcn_mfma_f32_16x16x32_bf16(a, b, c, 0, 0, 0);
}

DEVI void gld16(const void* g, void* l) {
    __builtin_amdgcn_global_load_lds(
        (const __attribute__((address_space(1))) unsigned int*)g,
        (__attribute__((address_space(3))) unsigned int*)l, 16, 0, 0);
}

// ---------------- constants ----------------
#define Bsz 16
#define Ntok 1024
#define Cdim 1152
#define Hn 16
#define Dh 72
#define Dp 96
#define INNER 4608
#define Mrows (Bsz * Ntok)   // 16384

// workspace offsets (bytes)
#define OFF_QKV_WT  ((size_t)0)            // 3584 x 1152 x 2
#define OFF_PROJ_WT ((size_t)8257536)      // 1280 x 1152 x 2
#define OFF_FC1_WT  ((size_t)11206656)     // 4608 x 1152 x 2
#define OFF_FC2_WT  ((size_t)21823488)     // 1280 x 4608 x 2
#define OFF_H       ((size_t)33619968)     // 16384 x 1152 x 2
#define OFF_ATT     ((size_t)71368704)     // 16384 x 1152 x 2
#define OFF_Q       ((size_t)109117440)    // 256 x 1024 x 96 x 2
#define OFF_K       ((size_t)159449088)
#define OFF_VT      ((size_t)209780736)
#define OFF_HIDDEN  OFF_Q                  // aliases q/k/vt (dead by then)

// ---------------- pad-zero: q/k cols 72-95 per row; vt rows 72-79 per head ----------------
// Replaces the 151 MB full memset (only the MFMA-visible pad regions need zeros:
// QK reads cols 64-95 (ks=2); PV reads vt rows 64-79 (dt=4); rows 80-95 never read).
__global__ __launch_bounds__(256) void pad_zero(
    ushort_t* __restrict__ qb, ushort_t* __restrict__ kb, ushort_t* __restrict__ vtb)
{
    const int idx = blockIdx.x * 256 + threadIdx.x;
    const ushort4 z = {0, 0, 0, 0};
    if (blockIdx.y < 2) {
        // 262144 rows x 3 units of 8 ushorts at col 72
        const int row = idx / 3, c = idx % 3;
        ushort_t* p = (blockIdx.y == 0 ? qb : kb) + (size_t)row * Dp + 72 + c * 8;
        ((ushort4*)p)[0] = z; ((ushort4*)p)[1] = z;
    } else {
        // vt: 256 heads x 8 rows (72..79) x 128 units of 8
        if (idx < 256 * 8 * 128) {
            const int bh = idx >> 10;
            const int rem = idx & 1023;
            const int r = rem >> 7, u = rem & 127;
            ushort_t* p = vtb + (((size_t)(bh * Dp + 72 + r)) << 10) + u * 8;
            ((ushort4*)p)[0] = z; ((ushort4*)p)[1] = z;
        }
    }
}

// ---------------- weight transpose + cast: W[K][N] f32 -> Wt[N][K] bf16 ----------------
__global__ __launch_bounds__(256) void transpose_cast(
    const float* __restrict__ W, ushort_t* __restrict__ Wt, int K, int N)
{
    __shared__ float t[64][65];
    const int n0 = blockIdx.x * 64;
    const int k0 = blockIdx.y * 64;
    #pragma unroll
    for (int j = 0; j < 4; ++j) {
        int idx = threadIdx.x + j * 256;
        int r = idx >> 4;
        int c4 = idx & 15;
        float4 v = *(const float4*)&W[(size_t)(k0 + r) * N + n0 + c4 * 4];
        t[r][c4 * 4 + 0] = v.x; t[r][c4 * 4 + 1] = v.y;
        t[r][c4 * 4 + 2] = v.z; t[r][c4 * 4 + 3] = v.w;
    }
    __syncthreads();
    #pragma unroll
    for (int j = 0; j < 4; ++j) {
        int idx = threadIdx.x + j * 256;
        int rn = idx >> 4;
        int c4 = idx & 15;
        ushort4 o;
        o.x = f2bf(t[c4 * 4 + 0][rn]);
        o.y = f2bf(t[c4 * 4 + 1][rn]);
        o.z = f2bf(t[c4 * 4 + 2][rn]);
        o.w = f2bf(t[c4 * 4 + 3][rn]);
        *(ushort4*)&Wt[(size_t)(n0 + rn) * K + k0 + c4 * 4] = o;
    }
}

// ---------------- LayerNorm: f32 row(1152) -> bf16 ----------------
__global__ __launch_bounds__(256) void ln_kernel(
    const float* __restrict__ x, const float* __restrict__ g,
    const float* __restrict__ b, ushort_t* __restrict__ out)
{
    const int row = blockIdx.x;
    const int tid = threadIdx.x;
    const int lane = tid & 63, wid = tid >> 6;
    const float* xr = x + (size_t)row * Cdim;

    float4 v0 = ((const float4*)xr)[tid];
    float4 v1 = {0, 0, 0, 0};
    if (tid < 32) v1 = ((const float4*)xr)[256 + tid];
    float s  = v0.x + v0.y + v0.z + v0.w + v1.x + v1.y + v1.z + v1.w;
    float s2 = v0.x*v0.x + v0.y*v0.y + v0.z*v0.z + v0.w*v0.w
             + v1.x*v1.x + v1.y*v1.y + v1.z*v1.z + v1.w*v1.w;
    #pragma unroll
    for (int off = 32; off >= 1; off >>= 1) {
        s  += __shfl_xor(s, off);
        s2 += __shfl_xor(s2, off);
    }
    __shared__ float red[8];
    if (lane == 0) { red[wid] = s; red[4 + wid] = s2; }
    __syncthreads();
    s  = red[0] + red[1] + red[2] + red[3];
    s2 = red[4] + red[5] + red[6] + red[7];
    const float mu = s * (1.0f / Cdim);
    const float var = s2 * (1.0f / Cdim) - mu * mu;
    const float rs = rsqrtf(var + 1e-6f);

    ushort_t* orow = out + (size_t)row * Cdim;
    {
        float4 g4 = ((const float4*)g)[tid];
        float4 b4 = ((const float4*)b)[tid];
        ushort4 o;
        o.x = f2bf((v0.x - mu) * rs * g4.x + b4.x);
        o.y = f2bf((v0.y - mu) * rs * g4.y + b4.y);
        o.z = f2bf((v0.z - mu) * rs * g4.z + b4.z);
        o.w = f2bf((v0.w - mu) * rs * g4.w + b4.w);
        ((ushort4*)orow)[tid] = o;
    }
    if (tid < 32) {
        float4 g4 = ((const float4*)g)[256 + tid];
        float4 b4 = ((const float4*)b)[256 + tid];
        ushort4 o;
        o.x = f2bf((v1.x - mu) * rs * g4.x + b4.x);
        o.y = f2bf((v1.y - mu) * rs * g4.y + b4.y);
        o.z = f2bf((v1.z - mu) * rs * g4.z + b4.z);
        o.w = f2bf((v1.w - mu) * rs * g4.w + b4.w);
        ((ushort4*)orow)[256 + tid] = o;
    }
}

// ---------------- GEMM: persistent blocks, 256x128 tile, BK=64, ring-3 LDS ----------------
// (unchanged — proven: single barrier/K-step, vmcnt(6), 0 conflicts)
enum { EPI_QKV = 0, EPI_PROJ = 1, EPI_FC1 = 2, EPI_FC2 = 3 };

#define TBM 256
#define TBN 128
#define TBK 64
#define BUFB 49152   // bytes per ring buffer (A 32768 + B 16384)

template<int EPI, int N, int K>
__global__ __launch_bounds__(512, 1) void gemm_bt(
    const ushort_t* __restrict__ A, const ushort_t* __restrict__ Bt,
    const float* __restrict__ bias, const float* __restrict__ resid,
    float* __restrict__ outf, ushort_t* __restrict__ outb,
    ushort_t* __restrict__ outq, ushort_t* __restrict__ outk, ushort_t* __restrict__ outv)
{
    __shared__ ushort_t smem[3 * BUFB / 2];   // 144 KB
    const int tid = threadIdx.x;
    const int lane = tid & 63, wid = tid >> 6;
    const int wr = wid >> 1, wc = wid & 1;     // 4M x 2N waves, 64x64 out each
    const int fr = lane & 15, fq = lane >> 4;
    const int bid = blockIdx.x;
    constexpr int NTt = K / TBK;               // K-steps per tile
    constexpr int NTN = N / TBN;               // n-tiles
    constexpr int TT  = (Mrows / TBM) * NTN;   // total tiles (64 * NTN)

    size_t srcA[4]; int dstA[4];
    #pragma unroll
    for (int r = 0; r < 4; ++r) {
        const int chunk = r * 512 + tid;
        const int row = chunk >> 3, slot = chunk & 7;
        srcA[r] = (size_t)row * K + (slot ^ (row & 7)) * 8;
        dstA[r] = chunk * 16;
    }
    size_t srcB[2]; int dstB[2];
    #pragma unroll
    for (int r = 0; r < 2; ++r) {
        const int chunk = r * 512 + tid;
        const int row = chunk >> 3, slot = chunk & 7;
        srcB[r] = (size_t)row * K + (slot ^ (row & 7)) * 8;
        dstB[r] = 32768 + chunk * 16;
    }
    const int swz = (fr & 7) << 4;
    int aoff[4][2], boff[4][2];
    #pragma unroll
    for (int kh = 0; kh < 2; ++kh) {
        const int colb = (kh * 64 + fq * 16) ^ swz;
        #pragma unroll
        for (int i = 0; i < 4; ++i) {
            aoff[i][kh] = (wr * 64 + i * 16 + fr) * 128 + colb;
            boff[i][kh] = 32768 + (wc * 64 + i * 16 + fr) * 128 + colb;
        }
    }

    const int nj = (TT - bid + 255) / 256;
    const int total_u = nj * NTt;

    int js = 0, ts = 0, sbuf = 0;
    const ushort_t *sAb, *sBb;
    auto setbases = [&](int j) {
        int s = bid + j * 256; if (s >= TT) s = bid;
        const int mt = s & 63, nt = s >> 6;
        sAb = A + (size_t)(mt * TBM) * K;
        sBb = Bt + (size_t)(nt * TBN) * K;
    };
    setbases(0);
    auto STAGE = [&]() {
        char* lb = (char*)smem + (size_t)sbuf * BUFB;
        const ushort_t* Ab = sAb + ts * TBK;
        const ushort_t* Bb = sBb + ts * TBK;
        #pragma unroll
        for (int r = 0; r < 4; ++r) gld16(Ab + srcA[r], lb + dstA[r]);
        #pragma unroll
        for (int r = 0; r < 2; ++r) gld16(Bb + srcB[r], lb + dstB[r]);
        sbuf = (sbuf == 2) ? 0 : sbuf + 1;
        if (++ts == NTt) { ts = 0; setbases(++js); }
    };

    f32x4 acc[4][4] = {};
    STAGE(); STAGE();

    int jc = 0, tc = 0, cbuf = 0;
    for (int u = 0; u < total_u; ++u) {
        asm volatile("s_waitcnt vmcnt(6)" ::: "memory");
        __builtin_amdgcn_s_barrier();
        __builtin_amdgcn_sched_barrier(0);
        STAGE();
        __builtin_amdgcn_sched_barrier(0);
        const char* lb = (const char*)smem + (size_t)cbuf * BUFB;
        #pragma unroll
        for (int kh = 0; kh < 2; ++kh) {
            short8 a[4], b[4];
            #pragma unroll
            for (int i = 0; i < 4; ++i) {
                a[i] = *(const short8*)(lb + aoff[i][kh]);
                b[i] = *(const short8*)(lb + boff[i][kh]);
            }
            __builtin_amdgcn_s_setprio(1);
            #pragma unroll
            for (int mi = 0; mi < 4; ++mi)
                #pragma unroll
                for (int ni = 0; ni < 4; ++ni)
                    acc[mi][ni] = mfma16(a[mi], b[ni], acc[mi][ni]);
            __builtin_amdgcn_s_setprio(0);
        }
        cbuf = (cbuf == 2) ? 0 : cbuf + 1;

        if (++tc == NTt) {
            tc = 0;
            const int s = bid + jc * 256;
            const int m0 = (s & 63) * TBM, n0 = (s >> 6) * TBN;
            #pragma unroll
            for (int mi = 0; mi < 4; ++mi) {
                #pragma unroll
                for (int ni = 0; ni < 4; ++ni) {
                    const int col = n0 + wc * 64 + ni * 16 + fr;
                    const int rbase = m0 + wr * 64 + mi * 16 + fq * 4;
                    #pragma unroll
                    for (int i = 0; i < 4; ++i) {
                        const int r = rbase + i;
                        float v = acc[mi][ni][i];
                        if (EPI == EPI_QKV) {
                            v += bias[col];
                            const int which = col / Cdim;
                            const int rc = col % Cdim;
                            const int h = rc / Dh, d = rc % Dh;
                            const int b2 = r >> 10, n = r & 1023;
                            const size_t head = (size_t)(b2 * Hn + h);
                            if (which == 0)      outq[(head * Ntok + n) * Dp + d] = f2bf(v);
                            else if (which == 1) outk[(head * Ntok + n) * Dp + d] = f2bf(v);
                            else                 outv[(head * Dp + d) * Ntok + n] = f2bf(v);
                        } else if (EPI == EPI_PROJ) {
                            v += bias[col] + resid[(size_t)r * N + col];
                            outf[(size_t)r * N + col] = v;
                        } else if (EPI == EPI_FC1) {
                            v += bias[col];
                            v = 0.5f * v * (1.0f + erff(v * 0.70710678118f));
                            outb[(size_t)r * N + col] = f2bf(v);
                        } else { // EPI_FC2
                            v += bias[col] + outf[(size_t)r * N + col];
                            outf[(size_t)r * N + col] = v;
                        }
                        acc[mi][ni][i] = 0.0f;
                    }
                }
            }
            ++jc;
        }
    }
}

// ---------------- flash attention: swapped-QK^T + cvt_pk + wide LDS bounce ----------------
// (Round-15 exact code — passed at absmax 0.03125. KVBLK=32 halves, K ping-pong,
// no-max softmax, cvt_pk pack, 2x ds_write_b64 + 1x b128 per tile, plds row 40.)
__global__ __launch_bounds__(256) void attn_kernel(
    const ushort_t* __restrict__ q, const ushort_t* __restrict__ k,
    const ushort_t* __restrict__ vt, ushort_t* __restrict__ out)
{
    const int tid = threadIdx.x;
    const int lane = tid & 63, wid = tid >> 6;
    const int bid = blockIdx.x;
    const int xcd = bid & 7;
    const int bh = (bid >> 6) * 8 + xcd;
    const int qblk = (bid >> 3) & 7;
    const int qbase = qblk * 128 + wid * 32;
    const int fr = lane & 15, fq = lane >> 4;
    const ushort_t* qh = q  + (size_t)bh * Ntok * Dp;
    const ushort_t* kh = k  + (size_t)bh * Ntok * Dp;
    const ushort_t* vh = vt + (size_t)bh * Dp * Ntok;

    short8 aq[2][3];
    #pragma unroll
    for (int t = 0; t < 2; ++t)
        #pragma unroll
        for (int ks = 0; ks < 3; ++ks)
            aq[t][ks] = *(const short8*)&qh[(size_t)(qbase + t * 16 + fr) * Dp + ks * 32 + fq * 8];

    f32x4 o[2][5] = {};
    float lsum[2] = {0.0f, 0.0f};   // per-lane: q = fr, partial over this lane's 8 k's

    __shared__ ushort_t plds[4][2][16][40];   // row stride 80B (16B-aligned reads)
    const float scale = 0.117851130f;   // 72^-0.5

    short8 kA0[3], kA1[3], kB0[3], kB1[3], v0[5], v1[5];
    #pragma unroll
    for (int ks = 0; ks < 3; ++ks) {
        kA0[ks] = *(const short8*)&kh[(size_t)(fr) * Dp + ks * 32 + fq * 8];
        kA1[ks] = *(const short8*)&kh[(size_t)(16 + fr) * Dp + ks * 32 + fq * 8];
    }

    #define ATTN_HALF(KB0, KB1, VV)                                                   \
    {                                                                                 \
        f32x4 s[2][2] = {};                                                           \
        __builtin_amdgcn_s_setprio(1);                                                \
        _Pragma("unroll")                                                             \
        for (int t = 0; t < 2; ++t)                                                   \
            _Pragma("unroll")                                                         \
            for (int ks = 0; ks < 3; ++ks) {                                          \
                s[t][0] = mfma16(KB0[ks], aq[t][ks], s[t][0]);                        \
                s[t][1] = mfma16(KB1[ks], aq[t][ks], s[t][1]);                        \
            }                                                                         \
        __builtin_amdgcn_s_setprio(0);                                                \
        _Pragma("unroll")                                                             \
        for (int t = 0; t < 2; ++t) {                                                 \
            float e0[4], e1[4];                                                       \
            _Pragma("unroll")                                                         \
            for (int i = 0; i < 4; ++i) {                                             \
                e0[i] = __expf(s[t][0][i] * scale);                                   \
                e1[i] = __expf(s[t][1][i] * scale);                                   \
            }                                                                         \
            lsum[t] += e0[0] + e0[1] + e0[2] + e0[3]                                  \
                     + e1[0] + e1[1] + e1[2] + e1[3];                                 \
            unsigned w0, w1, w2, w3;                                                  \
            asm("v_cvt_pk_bf16_f32 %0, %1, %2" : "=v"(w0) : "v"(e0[0]), "v"(e0[1])); \
            asm("v_cvt_pk_bf16_f32 %0, %1, %2" : "=v"(w1) : "v"(e0[2]), "v"(e0[3])); \
            asm("v_cvt_pk_bf16_f32 %0, %1, %2" : "=v"(w2) : "v"(e1[0]), "v"(e1[1])); \
            asm("v_cvt_pk_bf16_f32 %0, %1, %2" : "=v"(w3) : "v"(e1[2]), "v"(e1[3])); \
            uint2 lo; lo.x = w0; lo.y = w1;                                           \
            uint2 hi; hi.x = w2; hi.y = w3;                                           \
            *(uint2*)&plds[wid][t][fr][4 * fq]      = lo;                             \
            *(uint2*)&plds[wid][t][fr][16 + 4 * fq] = hi;                             \
        }                                                                             \
        short8 pa[2];                                                                 \
        _Pragma("unroll")                                                             \
        for (int t = 0; t < 2; ++t)                                                   \
            pa[t] = *(const short8*)&plds[wid][t][fr][8 * fq];                        \
        __builtin_amdgcn_s_setprio(1);                                                \
        _Pragma("unroll")                                                             \
        for (int dt = 0; dt < 5; ++dt)                                                \
            _Pragma("unroll")                                                         \
            for (int t = 0; t < 2; ++t)                                               \
                o[t][dt] = mfma16(pa[t], VV[dt], o[t][dt]);                           \
        __builtin_amdgcn_s_setprio(0);                                                \
    }

    for (int kv = 0; kv < Ntok; kv += 64) {
        // ---- half A: tile kv (K in kA, prefetch kB for kv+32, V0 at top)
        #pragma unroll
        for (int dt = 0; dt < 5; ++dt)
            v0[dt] = *(const short8*)&vh[(size_t)(dt * 16 + fr) * Ntok + kv + fq * 8];
        #pragma unroll
        for (int ks = 0; ks < 3; ++ks) {
            kB0[ks] = *(const short8*)&kh[(size_t)(kv + 32 + fr) * Dp + ks * 32 + fq * 8];
            kB1[ks] = *(const short8*)&kh[(size_t)(kv + 48 + fr) * Dp + ks * 32 + fq * 8];
        }
        ATTN_HALF(kA0, kA1, v0)

        // ---- half B: tile kv+32 (K in kB, prefetch kA for kv+64, V1 at top)
        #pragma unroll
        for (int dt = 0; dt < 5; ++dt)
            v1[dt] = *(const short8*)&vh[(size_t)(dt * 16 + fr) * Ntok + kv + 32 + fq * 8];
        if (kv + 64 < Ntok) {
            #pragma unroll
            for (int ks = 0; ks < 3; ++ks) {
                kA0[ks] = *(const short8*)&kh[(size_t)(kv + 64 + fr) * Dp + ks * 32 + fq * 8];
                kA1[ks] = *(const short8*)&kh[(size_t)(kv + 80 + fr) * Dp + ks * 32 + fq * 8];
            }
        }
        ATTN_HALF(kB0, kB1, v1)
    }
    #undef ATTN_HALF

    // reduce lsum over the k-distribution (fq = lane bits 4,5); all lanes end
    // with the full row-sum for q = fr.
    float Lred[2];
    #pragma unroll
    for (int t = 0; t < 2; ++t) {
        float s = lsum[t];
        s += __shfl_xor(s, 16);
        s += __shfl_xor(s, 32);
        Lred[t] = s;
    }

    const int b = bh >> 4, h = bh & 15;
    #pragma unroll
    for (int t = 0; t < 2; ++t) {
        float inv[4];
        #pragma unroll
        for (int i = 0; i < 4; ++i)
            inv[i] = 1.0f / __shfl(Lred[t], fq * 4 + i);   // q = fq*4+i held at lane fr==q
        #pragma unroll
        for (int dt = 0; dt < 5; ++dt) {
            const int d = dt * 16 + fr;
            if (d < Dh) {
                #pragma unroll
                for (int i = 0; i < 4; ++i) {
                    const size_t idx = ((size_t)(b * Ntok) + qbase + t * 16 + fq * 4 + i) * Cdim + h * Dh + d;
                    out[idx] = f2bf(o[t][dt][i] * inv[i]);
                }
            }
        }
    }
}

// ---------------- launch ----------------
extern "C" void kernel_launch(void* const* d_in, const int* in_sizes, int n_in,
                              void* d_out, int out_size, void* d_ws, size_t ws_size,
                              hipStream_t stream) {
    const float* x      = (const float*)d_in[0];
    const float* ln1_g  = (const float*)d_in[1];
    const float* ln1_b  = (const float*)d_in[2];
    const float* qkv_w  = (const float*)d_in[3];
    const float* qkv_b  = (const float*)d_in[4];
    const float* proj_w = (const float*)d_in[5];
    const float* proj_b = (const float*)d_in[6];
    const float* ln2_g  = (const float*)d_in[7];
    const float* ln2_b  = (const float*)d_in[8];
    const float* fc1_w  = (const float*)d_in[9];
    const float* fc1_b  = (const float*)d_in[10];
    const float* fc2_w  = (const float*)d_in[11];
    const float* fc2_b  = (const float*)d_in[12];

    char* ws = (char*)d_ws;
    ushort_t* qkv_wT  = (ushort_t*)(ws + OFF_QKV_WT);
    ushort_t* proj_wT = (ushort_t*)(ws + OFF_PROJ_WT);
    ushort_t* fc1_wT  = (ushort_t*)(ws + OFF_FC1_WT);
    ushort_t* fc2_wT  = (ushort_t*)(ws + OFF_FC2_WT);
    ushort_t* hbuf    = (ushort_t*)(ws + OFF_H);
    ushort_t* attnout = (ushort_t*)(ws + OFF_ATT);
    ushort_t* qb      = (ushort_t*)(ws + OFF_Q);
    ushort_t* kb      = (ushort_t*)(ws + OFF_K);
    ushort_t* vtb     = (ushort_t*)(ws + OFF_VT);
    ushort_t* hidden  = (ushort_t*)(ws + OFF_HIDDEN);
    float* out = (float*)d_out;

    // zero only the MFMA-visible pad regions (replaces 151 MB memset)
    pad_zero<<<dim3(3072, 3), 256, 0, stream>>>(qb, kb, vtb);

    transpose_cast<<<dim3(3 * Cdim / 64, Cdim / 64), 256, 0, stream>>>(qkv_w, qkv_wT, Cdim, 3 * Cdim);
    transpose_cast<<<dim3(Cdim / 64, Cdim / 64), 256, 0, stream>>>(proj_w, proj_wT, Cdim, Cdim);
    transpose_cast<<<dim3(INNER / 64, Cdim / 64), 256, 0, stream>>>(fc1_w, fc1_wT, Cdim, INNER);
    transpose_cast<<<dim3(Cdim / 64, INNER / 64), 256, 0, stream>>>(fc2_w, fc2_wT, INNER, Cdim);

    ln_kernel<<<Mrows, 256, 0, stream>>>(x, ln1_g, ln1_b, hbuf);

    gemm_bt<EPI_QKV, 3 * Cdim, Cdim><<<256, 512, 0, stream>>>(
        hbuf, qkv_wT, qkv_b, nullptr, nullptr, nullptr, qb, kb, vtb);

    attn_kernel<<<2048, 256, 0, stream>>>(qb, kb, vtb, attnout);

    gemm_bt<EPI_PROJ, Cdim, Cdim><<<256, 512, 0, stream>>>(
        attnout, proj_wT, proj_b, x, out, nullptr, nullptr, nullptr, nullptr);

    ln_kernel<<<Mrows, 256, 0, stream>>>(out, ln2_g, ln2_b, hbuf);

    gemm_bt<EPI_FC1, INNER, Cdim><<<256, 512, 0, stream>>>(
        hbuf, fc1_wT, fc1_b, nullptr, nullptr, hidden, nullptr, nullptr, nullptr);

    gemm_bt<EPI_FC2, Cdim, INNER><<<256, 512, 0, stream>>>(
        hidden, fc2_wT, fc2_b, nullptr, out, nullptr, nullptr, nullptr, nullptr);
}

// Round 18
// 1016.201 us; speedup vs baseline: 1.0431x; 1.0229x over previous
//
#include <hip/hip_runtime.h>
#include <hip/hip_bf16.h>

typedef unsigned short ushort_t;
using short8 = __attribute__((ext_vector_type(8))) short;
using f32x4  = __attribute__((ext_vector_type(4))) float;

#define DEVI __device__ __forceinline__

DEVI ushort_t f2bf(float f) {
    union { float f; unsigned u; } c; c.f = f;
    unsigned u = c.u;
    return (ushort_t)((u + 0x7FFF + ((u >> 16) & 1)) >> 16);
}

DEVI f32x4 mfma16(short8 a, short8 b, f32x4 c) {
    return __builtin_amdgcn_mfma_f32_16x16x32_bf16(a, b, c, 0, 0, 0);
}

DEVI void gld16(const void* g, void* l) {
    __builtin_amdgcn_global_load_lds(
        (const __attribute__((address_space(1))) unsigned int*)g,
        (__attribute__((address_space(3))) unsigned int*)l, 16, 0, 0);
}

// ---------------- constants ----------------
#define Bsz 16
#define Ntok 1024
#define Cdim 1152
#define Hn 16
#define Dh 72
#define Dp 96
#define INNER 4608
#define Mrows (Bsz * Ntok)   // 16384

// workspace offsets (bytes)
#define OFF_QKV_WT  ((size_t)0)            // 3584 x 1152 x 2
#define OFF_PROJ_WT ((size_t)8257536)      // 1280 x 1152 x 2
#define OFF_FC1_WT  ((size_t)11206656)     // 4640 x 1152 slack
#define OFF_FC2_WT  ((size_t)21823488)     // 1280 x 4608 x 2
#define OFF_H       ((size_t)33619968)     // 16384 x 1152 x 2
#define OFF_ATT     ((size_t)71368704)     // 16384 x 1152 x 2
#define OFF_Q       ((size_t)109117440)    // 256 x 1024 x 96 x 2
#define OFF_K       ((size_t)159449088)
#define OFF_VT      ((size_t)209780736)
#define OFF_HIDDEN  OFF_Q                  // aliases q/k/vt (dead by then)

// ---------------- pad-zero: q/k cols 72-95 per row; vt rows 72-79 per head ----------------
__global__ __launch_bounds__(256) void pad_zero(
    ushort_t* __restrict__ qb, ushort_t* __restrict__ kb, ushort_t* __restrict__ vtb)
{
    const int idx = blockIdx.x * 256 + threadIdx.x;
    const ushort4 z = {0, 0, 0, 0};
    if (blockIdx.y < 2) {
        const int row = idx / 3, c = idx % 3;
        ushort_t* p = (blockIdx.y == 0 ? qb : kb) + (size_t)row * Dp + 72 + c * 8;
        ((ushort4*)p)[0] = z; ((ushort4*)p)[1] = z;
    } else {
        if (idx < 256 * 8 * 128) {
            const int bh = idx >> 10;
            const int rem = idx & 1023;
            const int r = rem >> 7, u = rem & 127;
            ushort_t* p = vtb + (((size_t)(bh * Dp + 72 + r)) << 10) + u * 8;
            ((ushort4*)p)[0] = z; ((ushort4*)p)[1] = z;
        }
    }
}

// ---------------- weight transpose + cast: W[K][N] f32 -> Wt[N][K] bf16 ----------------
__global__ __launch_bounds__(256) void transpose_cast(
    const float* __restrict__ W, ushort_t* __restrict__ Wt, int K, int N)
{
    __shared__ float t[64][65];
    const int n0 = blockIdx.x * 64;
    const int k0 = blockIdx.y * 64;
    #pragma unroll
    for (int j = 0; j < 4; ++j) {
        int idx = threadIdx.x + j * 256;
        int r = idx >> 4;
        int c4 = idx & 15;
        float4 v = *(const float4*)&W[(size_t)(k0 + r) * N + n0 + c4 * 4];
        t[r][c4 * 4 + 0] = v.x; t[r][c4 * 4 + 1] = v.y;
        t[r][c4 * 4 + 2] = v.z; t[r][c4 * 4 + 3] = v.w;
    }
    __syncthreads();
    #pragma unroll
    for (int j = 0; j < 4; ++j) {
        int idx = threadIdx.x + j * 256;
        int rn = idx >> 4;
        int c4 = idx & 15;
        ushort4 o;
        o.x = f2bf(t[c4 * 4 + 0][rn]);
        o.y = f2bf(t[c4 * 4 + 1][rn]);
        o.z = f2bf(t[c4 * 4 + 2][rn]);
        o.w = f2bf(t[c4 * 4 + 3][rn]);
        *(ushort4*)&Wt[(size_t)(n0 + rn) * K + k0 + c4 * 4] = o;
    }
}

// ---------------- LayerNorm: f32 row(1152) -> bf16 ----------------
__global__ __launch_bounds__(256) void ln_kernel(
    const float* __restrict__ x, const float* __restrict__ g,
    const float* __restrict__ b, ushort_t* __restrict__ out)
{
    const int row = blockIdx.x;
    const int tid = threadIdx.x;
    const int lane = tid & 63, wid = tid >> 6;
    const float* xr = x + (size_t)row * Cdim;

    float4 v0 = ((const float4*)xr)[tid];
    float4 v1 = {0, 0, 0, 0};
    if (tid < 32) v1 = ((const float4*)xr)[256 + tid];
    float s  = v0.x + v0.y + v0.z + v0.w + v1.x + v1.y + v1.z + v1.w;
    float s2 = v0.x*v0.x + v0.y*v0.y + v0.z*v0.z + v0.w*v0.w
             + v1.x*v1.x + v1.y*v1.y + v1.z*v1.z + v1.w*v1.w;
    #pragma unroll
    for (int off = 32; off >= 1; off >>= 1) {
        s  += __shfl_xor(s, off);
        s2 += __shfl_xor(s2, off);
    }
    __shared__ float red[8];
    if (lane == 0) { red[wid] = s; red[4 + wid] = s2; }
    __syncthreads();
    s  = red[0] + red[1] + red[2] + red[3];
    s2 = red[4] + red[5] + red[6] + red[7];
    const float mu = s * (1.0f / Cdim);
    const float var = s2 * (1.0f / Cdim) - mu * mu;
    const float rs = rsqrtf(var + 1e-6f);

    ushort_t* orow = out + (size_t)row * Cdim;
    {
        float4 g4 = ((const float4*)g)[tid];
        float4 b4 = ((const float4*)b)[tid];
        ushort4 o;
        o.x = f2bf((v0.x - mu) * rs * g4.x + b4.x);
        o.y = f2bf((v0.y - mu) * rs * g4.y + b4.y);
        o.z = f2bf((v0.z - mu) * rs * g4.z + b4.z);
        o.w = f2bf((v0.w - mu) * rs * g4.w + b4.w);
        ((ushort4*)orow)[tid] = o;
    }
    if (tid < 32) {
        float4 g4 = ((const float4*)g)[256 + tid];
        float4 b4 = ((const float4*)b)[256 + tid];
        ushort4 o;
        o.x = f2bf((v1.x - mu) * rs * g4.x + b4.x);
        o.y = f2bf((v1.y - mu) * rs * g4.y + b4.y);
        o.z = f2bf((v1.z - mu) * rs * g4.z + b4.z);
        o.w = f2bf((v1.w - mu) * rs * g4.w + b4.w);
        ((ushort4*)orow)[256 + tid] = o;
    }
}

// ---------------- GEMM: persistent blocks, 256xTN tile, BK=64, ring-3 LDS ----------------
// R7 schedule (single barrier/K-step, vmcnt(6), 0 conflicts). TN=128 or 96.
// TN=96 makes proj/fc2 tile counts exactly 3x256 (kills the 33% persistent-tail).
// B staging always covers 128 rows (over-stages 32 junk rows for TN=96) so every
// thread issues exactly 6 loads/stage -> vmcnt(6) arithmetic identical; ds_read
// only touches B rows < TN/2*2, junk never consumed.
enum { EPI_QKV = 0, EPI_PROJ = 1, EPI_FC1 = 2, EPI_FC2 = 3 };

#define TBM 256
#define TBK 64
#define BUFB 49152   // bytes per ring buffer (A 32768 + B 16384)

template<int EPI, int N, int K, int TN>
__global__ __launch_bounds__(512, 1) void gemm_bt(
    const ushort_t* __restrict__ A, const ushort_t* __restrict__ Bt,
    const float* __restrict__ bias, const float* __restrict__ resid,
    float* __restrict__ outf, ushort_t* __restrict__ outb,
    ushort_t* __restrict__ outq, ushort_t* __restrict__ outk, ushort_t* __restrict__ outv)
{
    __shared__ ushort_t smem[3 * BUFB / 2];   // 144 KB
    const int tid = threadIdx.x;
    const int lane = tid & 63, wid = tid >> 6;
    const int wr = wid >> 1, wc = wid & 1;     // 4M x 2N waves
    const int fr = lane & 15, fq = lane >> 4;
    const int bid = blockIdx.x;
    constexpr int NIF = TN / 32;               // per-wave N fragments (4 or 3)
    constexpr int NTt = K / TBK;
    constexpr int NTN = N / TN;
    constexpr int TT  = (Mrows / TBM) * NTN;

    size_t srcA[4]; int dstA[4];
    #pragma unroll
    for (int r = 0; r < 4; ++r) {
        const int chunk = r * 512 + tid;
        const int row = chunk >> 3, slot = chunk & 7;
        srcA[r] = (size_t)row * K + (slot ^ (row & 7)) * 8;
        dstA[r] = chunk * 16;
    }
    size_t srcB[2]; int dstB[2];
    #pragma unroll
    for (int r = 0; r < 2; ++r) {
        const int chunk = r * 512 + tid;
        const int row = chunk >> 3, slot = chunk & 7;
        srcB[r] = (size_t)row * K + (slot ^ (row & 7)) * 8;
        dstB[r] = 32768 + chunk * 16;
    }
    const int swz = (fr & 7) << 4;
    int aoff[4][2], boff[4][2];
    #pragma unroll
    for (int kh = 0; kh < 2; ++kh) {
        const int colb = (kh * 64 + fq * 16) ^ swz;
        #pragma unroll
        for (int i = 0; i < 4; ++i)
            aoff[i][kh] = (wr * 64 + i * 16 + fr) * 128 + colb;
        #pragma unroll
        for (int i = 0; i < NIF; ++i)
            boff[i][kh] = 32768 + (wc * (TN / 2) + i * 16 + fr) * 128 + colb;
    }

    const int nj = (TT - bid + 255) / 256;
    const int total_u = nj * NTt;

    int js = 0, ts = 0, sbuf = 0;
    const ushort_t *sAb, *sBb;
    auto setbases = [&](int j) {
        int s = bid + j * 256; if (s >= TT) s = bid;
        const int mt = s & 63, nt = s >> 6;
        sAb = A + (size_t)(mt * TBM) * K;
        sBb = Bt + (size_t)(nt * TN) * K;
    };
    setbases(0);
    auto STAGE = [&]() {
        char* lb = (char*)smem + (size_t)sbuf * BUFB;
        const ushort_t* Ab = sAb + ts * TBK;
        const ushort_t* Bb = sBb + ts * TBK;
        #pragma unroll
        for (int r = 0; r < 4; ++r) gld16(Ab + srcA[r], lb + dstA[r]);
        #pragma unroll
        for (int r = 0; r < 2; ++r) gld16(Bb + srcB[r], lb + dstB[r]);
        sbuf = (sbuf == 2) ? 0 : sbuf + 1;
        if (++ts == NTt) { ts = 0; setbases(++js); }
    };

    f32x4 acc[4][4] = {};
    STAGE(); STAGE();

    int jc = 0, tc = 0, cbuf = 0;
    for (int u = 0; u < total_u; ++u) {
        asm volatile("s_waitcnt vmcnt(6)" ::: "memory");
        __builtin_amdgcn_s_barrier();
        __builtin_amdgcn_sched_barrier(0);
        STAGE();
        __builtin_amdgcn_sched_barrier(0);
        const char* lb = (const char*)smem + (size_t)cbuf * BUFB;
        #pragma unroll
        for (int kh = 0; kh < 2; ++kh) {
            short8 a[4], b[4];
            #pragma unroll
            for (int i = 0; i < 4; ++i)
                a[i] = *(const short8*)(lb + aoff[i][kh]);
            #pragma unroll
            for (int i = 0; i < NIF; ++i)
                b[i] = *(const short8*)(lb + boff[i][kh]);
            __builtin_amdgcn_s_setprio(1);
            #pragma unroll
            for (int mi = 0; mi < 4; ++mi)
                #pragma unroll
                for (int ni = 0; ni < NIF; ++ni)
                    acc[mi][ni] = mfma16(a[mi], b[ni], acc[mi][ni]);
            __builtin_amdgcn_s_setprio(0);
        }
        cbuf = (cbuf == 2) ? 0 : cbuf + 1;

        if (++tc == NTt) {
            tc = 0;
            const int s = bid + jc * 256;
            const int m0 = (s & 63) * TBM, n0 = (s >> 6) * TN;
            #pragma unroll
            for (int mi = 0; mi < 4; ++mi) {
                #pragma unroll
                for (int ni = 0; ni < NIF; ++ni) {
                    const int col = n0 + wc * (TN / 2) + ni * 16 + fr;
                    const int rbase = m0 + wr * 64 + mi * 16 + fq * 4;
                    #pragma unroll
                    for (int i = 0; i < 4; ++i) {
                        const int r = rbase + i;
                        float v = acc[mi][ni][i];
                        if (EPI == EPI_QKV) {
                            v += bias[col];
                            const int which = col / Cdim;
                            const int rc = col % Cdim;
                            const int h = rc / Dh, d = rc % Dh;
                            const int b2 = r >> 10, n = r & 1023;
                            const size_t head = (size_t)(b2 * Hn + h);
                            if (which == 0)      outq[(head * Ntok + n) * Dp + d] = f2bf(v);
                            else if (which == 1) outk[(head * Ntok + n) * Dp + d] = f2bf(v);
                            else                 outv[(head * Dp + d) * Ntok + n] = f2bf(v);
                        } else if (EPI == EPI_PROJ) {
                            v += bias[col] + resid[(size_t)r * N + col];
                            outf[(size_t)r * N + col] = v;
                        } else if (EPI == EPI_FC1) {
                            v += bias[col];
                            v = 0.5f * v * (1.0f + erff(v * 0.70710678118f));
                            outb[(size_t)r * N + col] = f2bf(v);
                        } else { // EPI_FC2
                            v += bias[col] + outf[(size_t)r * N + col];
                            outf[(size_t)r * N + col] = v;
                        }
                        acc[mi][ni][i] = 0.0f;
                    }
                }
            }
            ++jc;
        }
    }
}

// ---------------- flash attention (frozen at Round-15 structure) ----------------
__global__ __launch_bounds__(256) void attn_kernel(
    const ushort_t* __restrict__ q, const ushort_t* __restrict__ k,
    const ushort_t* __restrict__ vt, ushort_t* __restrict__ out)
{
    const int tid = threadIdx.x;
    const int lane = tid & 63, wid = tid >> 6;
    const int bid = blockIdx.x;
    const int xcd = bid & 7;
    const int bh = (bid >> 6) * 8 + xcd;
    const int qblk = (bid >> 3) & 7;
    const int qbase = qblk * 128 + wid * 32;
    const int fr = lane & 15, fq = lane >> 4;
    const ushort_t* qh = q  + (size_t)bh * Ntok * Dp;
    const ushort_t* kh = k  + (size_t)bh * Ntok * Dp;
    const ushort_t* vh = vt + (size_t)bh * Dp * Ntok;

    short8 aq[2][3];
    #pragma unroll
    for (int t = 0; t < 2; ++t)
        #pragma unroll
        for (int ks = 0; ks < 3; ++ks)
            aq[t][ks] = *(const short8*)&qh[(size_t)(qbase + t * 16 + fr) * Dp + ks * 32 + fq * 8];

    f32x4 o[2][5] = {};
    float lsum[2] = {0.0f, 0.0f};

    __shared__ ushort_t plds[4][2][16][40];
    const float scale = 0.117851130f;   // 72^-0.5

    short8 kA0[3], kA1[3], kB0[3], kB1[3], v0[5], v1[5];
    #pragma unroll
    for (int ks = 0; ks < 3; ++ks) {
        kA0[ks] = *(const short8*)&kh[(size_t)(fr) * Dp + ks * 32 + fq * 8];
        kA1[ks] = *(const short8*)&kh[(size_t)(16 + fr) * Dp + ks * 32 + fq * 8];
    }

    #define ATTN_HALF(KB0, KB1, VV)                                                   \
    {                                                                                 \
        f32x4 s[2][2] = {};                                                           \
        __builtin_amdgcn_s_setprio(1);                                                \
        _Pragma("unroll")                                                             \
        for (int t = 0; t < 2; ++t)                                                   \
            _Pragma("unroll")                                                         \
            for (int ks = 0; ks < 3; ++ks) {                                          \
                s[t][0] = mfma16(KB0[ks], aq[t][ks], s[t][0]);                        \
                s[t][1] = mfma16(KB1[ks], aq[t][ks], s[t][1]);                        \
            }                                                                         \
        __builtin_amdgcn_s_setprio(0);                                                \
        _Pragma("unroll")                                                             \
        for (int t = 0; t < 2; ++t) {                                                 \
            float e0[4], e1[4];                                                       \
            _Pragma("unroll")                                                         \
            for (int i = 0; i < 4; ++i) {                                             \
                e0[i] = __expf(s[t][0][i] * scale);                                   \
                e1[i] = __expf(s[t][1][i] * scale);                                   \
            }                                                                         \
            lsum[t] += e0[0] + e0[1] + e0[2] + e0[3]                                  \
                     + e1[0] + e1[1] + e1[2] + e1[3];                                 \
            unsigned w0, w1, w2, w3;                                                  \
            asm("v_cvt_pk_bf16_f32 %0, %1, %2" : "=v"(w0) : "v"(e0[0]), "v"(e0[1])); \
            asm("v_cvt_pk_bf16_f32 %0, %1, %2" : "=v"(w1) : "v"(e0[2]), "v"(e0[3])); \
            asm("v_cvt_pk_bf16_f32 %0, %1, %2" : "=v"(w2) : "v"(e1[0]), "v"(e1[1])); \
            asm("v_cvt_pk_bf16_f32 %0, %1, %2" : "=v"(w3) : "v"(e1[2]), "v"(e1[3])); \
            uint2 lo; lo.x = w0; lo.y = w1;                                           \
            uint2 hi; hi.x = w2; hi.y = w3;                                           \
            *(uint2*)&plds[wid][t][fr][4 * fq]      = lo;                             \
            *(uint2*)&plds[wid][t][fr][16 + 4 * fq] = hi;                             \
        }                                                                             \
        short8 pa[2];                                                                 \
        _Pragma("unroll")                                                             \
        for (int t = 0; t < 2; ++t)                                                   \
            pa[t] = *(const short8*)&plds[wid][t][fr][8 * fq];                        \
        __builtin_amdgcn_s_setprio(1);                                                \
        _Pragma("unroll")                                                             \
        for (int dt = 0; dt < 5; ++dt)                                                \
            _Pragma("unroll")                                                         \
            for (int t = 0; t < 2; ++t)                                               \
                o[t][dt] = mfma16(pa[t], VV[dt], o[t][dt]);                           \
        __builtin_amdgcn_s_setprio(0);                                                \
    }

    for (int kv = 0; kv < Ntok; kv += 64) {
        #pragma unroll
        for (int dt = 0; dt < 5; ++dt)
            v0[dt] = *(const short8*)&vh[(size_t)(dt * 16 + fr) * Ntok + kv + fq * 8];
        #pragma unroll
        for (int ks = 0; ks < 3; ++ks) {
            kB0[ks] = *(const short8*)&kh[(size_t)(kv + 32 + fr) * Dp + ks * 32 + fq * 8];
            kB1[ks] = *(const short8*)&kh[(size_t)(kv + 48 + fr) * Dp + ks * 32 + fq * 8];
        }
        ATTN_HALF(kA0, kA1, v0)

        #pragma unroll
        for (int dt = 0; dt < 5; ++dt)
            v1[dt] = *(const short8*)&vh[(size_t)(dt * 16 + fr) * Ntok + kv + 32 + fq * 8];
        if (kv + 64 < Ntok) {
            #pragma unroll
            for (int ks = 0; ks < 3; ++ks) {
                kA0[ks] = *(const short8*)&kh[(size_t)(kv + 64 + fr) * Dp + ks * 32 + fq * 8];
                kA1[ks] = *(const short8*)&kh[(size_t)(kv + 80 + fr) * Dp + ks * 32 + fq * 8];
            }
        }
        ATTN_HALF(kB0, kB1, v1)
    }
    #undef ATTN_HALF

    float Lred[2];
    #pragma unroll
    for (int t = 0; t < 2; ++t) {
        float s = lsum[t];
        s += __shfl_xor(s, 16);
        s += __shfl_xor(s, 32);
        Lred[t] = s;
    }

    const int b = bh >> 4, h = bh & 15;
    #pragma unroll
    for (int t = 0; t < 2; ++t) {
        float inv[4];
        #pragma unroll
        for (int i = 0; i < 4; ++i)
            inv[i] = 1.0f / __shfl(Lred[t], fq * 4 + i);
        #pragma unroll
        for (int dt = 0; dt < 5; ++dt) {
            const int d = dt * 16 + fr;
            if (d < Dh) {
                #pragma unroll
                for (int i = 0; i < 4; ++i) {
                    const size_t idx = ((size_t)(b * Ntok) + qbase + t * 16 + fq * 4 + i) * Cdim + h * Dh + d;
                    out[idx] = f2bf(o[t][dt][i] * inv[i]);
                }
            }
        }
    }
}

// ---------------- launch ----------------
extern "C" void kernel_launch(void* const* d_in, const int* in_sizes, int n_in,
                              void* d_out, int out_size, void* d_ws, size_t ws_size,
                              hipStream_t stream) {
    const float* x      = (const float*)d_in[0];
    const float* ln1_g  = (const float*)d_in[1];
    const float* ln1_b  = (const float*)d_in[2];
    const float* qkv_w  = (const float*)d_in[3];
    const float* qkv_b  = (const float*)d_in[4];
    const float* proj_w = (const float*)d_in[5];
    const float* proj_b = (const float*)d_in[6];
    const float* ln2_g  = (const float*)d_in[7];
    const float* ln2_b  = (const float*)d_in[8];
    const float* fc1_w  = (const float*)d_in[9];
    const float* fc1_b  = (const float*)d_in[10];
    const float* fc2_w  = (const float*)d_in[11];
    const float* fc2_b  = (const float*)d_in[12];

    char* ws = (char*)d_ws;
    ushort_t* qkv_wT  = (ushort_t*)(ws + OFF_QKV_WT);
    ushort_t* proj_wT = (ushort_t*)(ws + OFF_PROJ_WT);
    ushort_t* fc1_wT  = (ushort_t*)(ws + OFF_FC1_WT);
    ushort_t* fc2_wT  = (ushort_t*)(ws + OFF_FC2_WT);
    ushort_t* hbuf    = (ushort_t*)(ws + OFF_H);
    ushort_t* attnout = (ushort_t*)(ws + OFF_ATT);
    ushort_t* qb      = (ushort_t*)(ws + OFF_Q);
    ushort_t* kb      = (ushort_t*)(ws + OFF_K);
    ushort_t* vtb     = (ushort_t*)(ws + OFF_VT);
    ushort_t* hidden  = (ushort_t*)(ws + OFF_HIDDEN);
    float* out = (float*)d_out;

    // zero only the MFMA-visible pad regions (replaces 151 MB memset)
    pad_zero<<<dim3(3072, 3), 256, 0, stream>>>(qb, kb, vtb);

    transpose_cast<<<dim3(3 * Cdim / 64, Cdim / 64), 256, 0, stream>>>(qkv_w, qkv_wT, Cdim, 3 * Cdim);
    transpose_cast<<<dim3(Cdim / 64, Cdim / 64), 256, 0, stream>>>(proj_w, proj_wT, Cdim, Cdim);
    transpose_cast<<<dim3(INNER / 64, Cdim / 64), 256, 0, stream>>>(fc1_w, fc1_wT, Cdim, INNER);
    transpose_cast<<<dim3(Cdim / 64, INNER / 64), 256, 0, stream>>>(fc2_w, fc2_wT, INNER, Cdim);

    ln_kernel<<<Mrows, 256, 0, stream>>>(x, ln1_g, ln1_b, hbuf);

    gemm_bt<EPI_QKV, 3 * Cdim, Cdim, 128><<<256, 512, 0, stream>>>(
        hbuf, qkv_wT, qkv_b, nullptr, nullptr, nullptr, qb, kb, vtb);

    attn_kernel<<<2048, 256, 0, stream>>>(qb, kb, vtb, attnout);

    gemm_bt<EPI_PROJ, Cdim, Cdim, 96><<<256, 512, 0, stream>>>(
        attnout, proj_wT, proj_b, x, out, nullptr, nullptr, nullptr, nullptr);

    ln_kernel<<<Mrows, 256, 0, stream>>>(out, ln2_g, ln2_b, hbuf);

    gemm_bt<EPI_FC1, INNER, Cdim, 128><<<256, 512, 0, stream>>>(
        hbuf, fc1_wT, fc1_b, nullptr, nullptr, hidden, nullptr, nullptr, nullptr);

    gemm_bt<EPI_FC2, Cdim, INNER, 96><<<256, 512, 0, stream>>>(
        hidden, fc2_wT, fc2_b, nullptr, out, nullptr, nullptr, nullptr, nullptr);
}